// Round 9
// baseline (294.426 us; speedup 1.0000x reference)
//
#include <hip/hip_runtime.h>
#include <hip/hip_bf16.h>

// Problem constants (SOnEquivalentLayer)
#define N_ATOMS 20000
#define N_EDGES 200000
#define CCH     64      // channels
#define KRBF    20      // radial features
#define RCUT    5.0f
#define INV_NORM 0.1f   // 1/norm_factor
#define PI_F    3.14159265358979323846f
#define MCAP    20000   // message pool capacity (~6x expected ~3.3k active edges)
#define ACAP    10000   // active-atom capacity (~3x expected ~3.0k)
#define XSTRIDE 856     // bf16 elems per atom row in LDS (832 + 24 pad)
#define FLAT    832     // 13*64 values per atom, t-flat order: [64 t0 | 192 t1(c,a) | 576 t2(c,e)]

typedef short v8s __attribute__((ext_vector_type(8)));   // 8 bf16 MFMA A/B frag
typedef short v4s __attribute__((ext_vector_type(4)));   // 4 bf16
typedef float v4f __attribute__((ext_vector_type(4)));   // 4 fp32 MFMA C/D frag

__device__ __forceinline__ float sigm(float x) { return 1.0f / (1.0f + __expf(-x)); }

__device__ __forceinline__ short f2bf(float x) {
    union { float f; unsigned u; } v; v.f = x;
    unsigned r = v.u + 0x7FFFu + ((v.u >> 16) & 1u);
    return (short)(r >> 16);
}
__device__ __forceinline__ float bf2f(short b) {
    union { unsigned u; float f; } v; v.u = ((unsigned)(unsigned short)b) << 16;
    return v.f;
}

// ---------------------------------------------------------------------------
// Phase A: thread-per-edge cutoff filter -> flat compacted message pool
// + CAS first-touch compact-slot allocation. ~1.65% edges survive.
// ---------------------------------------------------------------------------
__global__ __launch_bounds__(256) void edge_filter_kernel(
    const float* __restrict__ coords,
    const int*   __restrict__ edge_index,
    float4*      __restrict__ mu,
    float*       __restrict__ mb,
    int*         __restrict__ maj,
    int*         __restrict__ mai,
    int*         __restrict__ slotOf,
    int*         __restrict__ counters)
{
    const int e = blockIdx.x * 256 + threadIdx.x;
    if (e >= N_EDGES) return;
    const int ai = edge_index[e];
    const int aj = edge_index[N_EDGES + e];

    const float rx = coords[aj * 3 + 0] - coords[ai * 3 + 0];
    const float ry = coords[aj * 3 + 1] - coords[ai * 3 + 1];
    const float rz = coords[aj * 3 + 2] - coords[ai * 3 + 2];
    const float d  = sqrtf(rx * rx + ry * ry + rz * rz + 1e-12f);
    if (d >= RCUT) return;   // fc == 0 exactly -> zero contribution

    const float inv_d = 1.0f / d;
    const float base  = PI_F * (d * (1.0f / RCUT));
    const float fc    = 0.5f * (cosf(base) + 1.0f);
    const float coef  = 0.632455532033676f * fc * inv_d * INV_NORM;

    const int slot = atomicAdd(&counters[0], 1);
    if (slot >= MCAP) return;
    mu[slot]  = make_float4(rx * inv_d, ry * inv_d, rz * inv_d, coef);
    mb[slot]  = base;
    maj[slot] = aj;
    mai[slot] = ai;
    if (atomicCAS(&slotOf[ai], -1, -2) == -1)
        slotOf[ai] = atomicAdd(&counters[1], 1);
}

// ---------------------------------------------------------------------------
// W-fragment precompute: one-time gather of w0/w1/w2 into bf16 MFMA B-frags,
// layout [wid][way][half][lane][8] so si_mfma reads 6 coalesced b128 loads.
// ---------------------------------------------------------------------------
__global__ __launch_bounds__(256) void wfrag_kernel(
    const float* __restrict__ w0,
    const float* __restrict__ w1,
    const float* __restrict__ w2,
    short*       __restrict__ wfpre)        // [4*3*2*64*8]
{
    const int id = blockIdx.x * 256 + threadIdx.x;   // 48*256 = 12288
    const int j    = id & 7;
    const int lane = (id >> 3) & 63;
    const int h    = (id >> 9) & 1;
    const int rest = id >> 10;               // wid*3 + w, in [0,12)
    const int w    = rest % 3;
    const int wid  = rest / 3;
    const float* Ws = (w == 0) ? w0 : (w == 1) ? w1 : w2;
    const int k = h * 32 + (lane >> 4) * 8 + j;      // k index (input channel)
    const int o = wid * 16 + (lane & 15);            // output channel
    wfpre[id] = f2bf(Ws[k * CCH + o]);
}

// ---------------------------------------------------------------------------
// Phase B: wave-per-message scan; atomicAdd into zeroed compact agg in
// T-FLAT layout: agg[slot*832 + {c | 64+c*3+a | 256+c*9+e}].
// ---------------------------------------------------------------------------
__global__ __launch_bounds__(256, 4) void msg_scan_kernel(
    const float* __restrict__ t0,
    const float* __restrict__ t1,
    const float* __restrict__ t2,
    const float* __restrict__ rbf_w,
    const float4* __restrict__ mu,
    const float* __restrict__ mb,
    const int*   __restrict__ maj,
    const int*   __restrict__ mai,
    const int*   __restrict__ slotOf,
    const int*   __restrict__ counters,
    float*       __restrict__ agg)          // [ACAP * 832], zero-init
{
    const int w    = (int)((blockIdx.x * 256 + threadIdx.x) >> 6);
    const int c    = threadIdx.x & 63;
    const int nw   = gridDim.x * 4;
    const int nMsg = min(counters[0], MCAP);

    for (int s = w; s < nMsg; s += nw) {
        const float4 U   = mu[s];
        const float base = mb[s];
        const int   aj   = maj[s];
        const int   ai   = mai[s];
        const int   sIdx = slotOf[ai];
        if ((unsigned)sIdx >= ACAP) continue;

        float rbf[KRBF];
#pragma unroll
        for (int kk = 0; kk < KRBF; kk++)
            rbf[kk] = U.w * __sinf((float)(kk + 1) * base);

        float fn[11];
#pragma unroll 1
        for (int k = 0; k < 11; k++) {
            float acc = 0.0f;
#pragma unroll
            for (int kk = 0; kk < KRBF; kk++)
                acc += rbf[kk] * rbf_w[k * (KRBF * CCH) + kk * CCH + c];
            fn[k] = acc;
        }

        const int cj = aj * CCH + c;
        const float s0 = t0[cj];
        float v[3];
#pragma unroll
        for (int a = 0; a < 3; a++) v[a] = t1[cj * 3 + a];
        float M[9];
#pragma unroll
        for (int e = 0; e < 9; e++) M[e] = t2[cj * 9 + e];

        const float u[3] = { U.x, U.y, U.z };
        const float dvu = v[0] * u[0] + v[1] * u[1] + v[2] * u[2];
        float Mu[3];
#pragma unroll
        for (int a = 0; a < 3; a++)
            Mu[a] = M[a * 3] * u[0] + M[a * 3 + 1] * u[1] + M[a * 3 + 2] * u[2];
        const float uMu = u[0] * Mu[0] + u[1] * Mu[1] + u[2] * Mu[2];

        float* dst = agg + (size_t)sIdx * FLAT;
        atomicAdd(&dst[c], fn[0] * s0 + fn[4] * dvu + fn[9] * uMu);
#pragma unroll
        for (int a = 0; a < 3; a++)
            atomicAdd(&dst[64 + c * 3 + a],
                      fn[1] * s0 * u[a] + fn[3] * v[a] + fn[6] * dvu * u[a] + fn[8] * Mu[a]);
#pragma unroll
        for (int a = 0; a < 3; a++) {
            const float ta = fn[2] * s0 * u[a] + fn[5] * v[a] + fn[10] * Mu[a];
#pragma unroll
            for (int b = 0; b < 3; b++)
                atomicAdd(&dst[256 + c * 9 + a * 3 + b], ta * u[b] + fn[7] * M[a * 3 + b]);
        }
    }
}

// ---------------------------------------------------------------------------
// Phase C: MFMA self-interaction, fully-coalesced VMEM.
// Staging: 13x dwordx4 loads (t-flat + matching agg) -> bf16 LDS transpose.
// MFMA: 26x mfma_f32_16x16x32_bf16; W-frags: 6 coalesced b128 loads.
// Epilogue: gate+residual RMW'd in-place into LDS (lane-owned positions),
// then 13x coalesced dwordx4 stores.
// ---------------------------------------------------------------------------
__global__ __launch_bounds__(256, 4) void si_mfma_kernel(
    const float* __restrict__ t0,
    const float* __restrict__ t1,
    const float* __restrict__ t2,
    const int*   __restrict__ slotOf,
    const float* __restrict__ agg,          // [ACAP * 832], t-flat layout
    const short* __restrict__ wfpre,        // [4][3][2][64][8] bf16
    const float* __restrict__ b0,
    const float* __restrict__ actw,
    float* __restrict__ out0,
    float* __restrict__ out1,
    float* __restrict__ out2)
{
    __shared__ __align__(16) short Xl[16 * XSTRIDE];   // 27.4 KB
    const int tid  = threadIdx.x;
    const int lane = tid & 63;
    const int wid  = tid >> 6;
    const int n0   = blockIdx.x * 16;

    const int ocol = wid * 16 + (lane & 15);
    // --- W fragments: 6 coalesced b128 loads ---
    v8s wf[3][2];
#pragma unroll
    for (int w = 0; w < 3; w++)
#pragma unroll
        for (int h = 0; h < 2; h++)
            wf[w][h] = *(const v8s*)&wfpre[(((wid * 3 + w) * 2 + h) * 64 + lane) * 8];

    // --- staging: 13 iters, dwordx4 loads, scattered-cheap LDS b16 writes ---
#pragma unroll 1
    for (int i = 0; i < 13; i++) {
        const int f4   = tid + i * 256;          // [0, 3328)
        const int atom = f4 / 208;               // 208 float4 per atom
        const int f    = (f4 - atom * 208) * 4;  // element offset in [0,832)
        const int n    = n0 + atom;
        const float* src;
        if (f < 64)       src = t0 + (size_t)n * 64 + f;
        else if (f < 256) src = t1 + (size_t)n * 192 + (f - 64);
        else              src = t2 + (size_t)n * 576 + (f - 256);
        float4 v = *(const float4*)src;
        const int slot = slotOf[n];
        if ((unsigned)slot < ACAP) {
            const float* ag = agg + (size_t)slot * FLAT + f;
            v.x += ag[0]; v.y += ag[1]; v.z += ag[2]; v.w += ag[3];
        }
        short* xr = &Xl[atom * XSTRIDE];
        if (f < 64) {
            v4s p; p[0] = f2bf(v.x); p[1] = f2bf(v.y); p[2] = f2bf(v.z); p[3] = f2bf(v.w);
            *(v4s*)&xr[f] = p;                   // plane 0 contiguous
        } else if (f < 256) {
            const int r0 = f - 64;
            const float vv[4] = { v.x, v.y, v.z, v.w };
#pragma unroll
            for (int j = 0; j < 4; j++) {
                const int rem = r0 + j;
                xr[(1 + rem % 3) * 64 + rem / 3] = f2bf(vv[j]);
            }
        } else {
            const int r0 = f - 256;
            const float vv[4] = { v.x, v.y, v.z, v.w };
#pragma unroll
            for (int j = 0; j < 4; j++) {
                const int rem = r0 + j;
                xr[(4 + rem % 9) * 64 + rem / 9] = f2bf(vv[j]);
            }
        }
    }
    __syncthreads();

    // --- 26 MFMAs: 13 planes x 2 k-halves ---
    v4f acc[13] = {};
    const int abase = (lane & 15) * XSTRIDE + (lane >> 4) * 8;
#pragma unroll
    for (int p = 0; p < 13; p++) {
        const int w = (p == 0) ? 0 : (p < 4 ? 1 : 2);
#pragma unroll
        for (int h = 0; h < 2; h++) {
            const v8s a = *(const v8s*)&Xl[abase + p * CCH + h * 32];
            acc[p] = __builtin_amdgcn_mfma_f32_16x16x32_bf16(a, wf[w][h], acc[p], 0, 0, 0);
        }
    }
    __syncthreads();   // all MFMA A-reads done before in-place overwrite

    // --- epilogue: gates + residual, RMW in-place (lane-owned positions) ---
    const float aw0  = actw[ocol];
    const float aw1  = actw[CCH + ocol];
    const float aw2  = actw[2 * CCH + ocol];
    const float bias = b0[ocol];
#pragma unroll
    for (int r = 0; r < 4; r++) {
        const int al = (lane >> 4) * 4 + r;      // atom-in-block (C/D row)
        short* xr = &Xl[al * XSTRIDE];

        const float y0 = acc[0][r] + bias;
        const float z0 = y0 * sigm(aw0 * y0);
        xr[ocol] = f2bf(z0 + bf2f(xr[ocol]));

        float nn = 1e-12f;
#pragma unroll
        for (int a = 0; a < 3; a++) nn += acc[1 + a][r] * acc[1 + a][r];
        const float g1 = sigm(aw1 * sqrtf(nn));
#pragma unroll
        for (int a = 0; a < 3; a++) {
            const int off = (1 + a) * CCH + ocol;
            xr[off] = f2bf(acc[1 + a][r] * g1 + bf2f(xr[off]));
        }

        float s2 = 1e-12f;
#pragma unroll
        for (int e = 0; e < 9; e++) s2 += acc[4 + e][r] * acc[4 + e][r];
        const float g2 = sigm(aw2 * sqrtf(s2));
#pragma unroll
        for (int e = 0; e < 9; e++) {
            const int off = (4 + e) * CCH + ocol;
            xr[off] = f2bf(acc[4 + e][r] * g2 + bf2f(xr[off]));
        }
    }
    __syncthreads();

    // --- store: 13 coalesced dwordx4 stores mirroring staging mapping ---
#pragma unroll 1
    for (int i = 0; i < 13; i++) {
        const int f4   = tid + i * 256;
        const int atom = f4 / 208;
        const int f    = (f4 - atom * 208) * 4;
        const int n    = n0 + atom;
        const short* xr = &Xl[atom * XSTRIDE];
        float4 v;
        float* dst;
        if (f < 64) {
            const v4s p = *(const v4s*)&xr[f];
            v.x = bf2f(p[0]); v.y = bf2f(p[1]); v.z = bf2f(p[2]); v.w = bf2f(p[3]);
            dst = out0 + (size_t)n * 64 + f;
        } else if (f < 256) {
            const int r0 = f - 64;
            float vv[4];
#pragma unroll
            for (int j = 0; j < 4; j++) {
                const int rem = r0 + j;
                vv[j] = bf2f(xr[(1 + rem % 3) * 64 + rem / 3]);
            }
            v.x = vv[0]; v.y = vv[1]; v.z = vv[2]; v.w = vv[3];
            dst = out1 + (size_t)n * 192 + r0;
        } else {
            const int r0 = f - 256;
            float vv[4];
#pragma unroll
            for (int j = 0; j < 4; j++) {
                const int rem = r0 + j;
                vv[j] = bf2f(xr[(4 + rem % 9) * 64 + rem / 9]);
            }
            v.x = vv[0]; v.y = vv[1]; v.z = vv[2]; v.w = vv[3];
            dst = out2 + (size_t)n * 576 + r0;
        }
        *(float4*)dst = v;
    }
}

extern "C" void kernel_launch(void* const* d_in, const int* in_sizes, int n_in,
                              void* d_out, int out_size, void* d_ws, size_t ws_size,
                              hipStream_t stream) {
    const float* t0     = (const float*)d_in[0];
    const float* t1     = (const float*)d_in[1];
    const float* t2     = (const float*)d_in[2];
    const float* coords = (const float*)d_in[3];
    const int*   eidx   = (const int*)d_in[4];
    const float* rbfw   = (const float*)d_in[5];
    const float* w0     = (const float*)d_in[6];
    const float* b0     = (const float*)d_in[7];
    const float* w1     = (const float*)d_in[8];
    const float* w2     = (const float*)d_in[9];
    const float* actw   = (const float*)d_in[10];

    // Workspace: agg | mu | mb | maj | mai | wfpre | slotOf | counters
    float*  agg    = (float*)d_ws;                       // ACAP*832 floats (33.28 MB)
    float4* mu     = (float4*)(agg + (size_t)ACAP * FLAT);
    float*  mb     = (float*)(mu + MCAP);
    int*    maj    = (int*)(mb + MCAP);
    int*    mai    = maj + MCAP;
    short*  wfpre  = (short*)(mai + MCAP);               // 12288 bf16 (24.6 KB)
    int*    slotOf = (int*)(wfpre + 12288);
    int*    counters = slotOf + N_ATOMS;
    const size_t wsNeed = (size_t)ACAP * FLAT * 4 + (size_t)MCAP * 28
                        + 12288 * 2 + (size_t)N_ATOMS * 4 + 64;
    if (ws_size < wsNeed) return;

    hipMemsetAsync(agg, 0, (size_t)ACAP * FLAT * sizeof(float), stream);
    hipMemsetAsync(slotOf, 0xFF, (size_t)N_ATOMS * sizeof(int), stream);
    hipMemsetAsync(counters, 0, 2 * sizeof(int), stream);

    float* o0 = (float*)d_out;
    float* o1 = o0 + (size_t)N_ATOMS * CCH;
    float* o2 = o1 + (size_t)N_ATOMS * CCH * 3;

    edge_filter_kernel<<<(N_EDGES + 255) / 256, 256, 0, stream>>>(
        coords, eidx, mu, mb, maj, mai, slotOf, counters);

    wfrag_kernel<<<48, 256, 0, stream>>>(w0, w1, w2, wfpre);

    msg_scan_kernel<<<224, 256, 0, stream>>>(
        t0, t1, t2, rbfw, mu, mb, maj, mai, slotOf, counters, agg);

    si_mfma_kernel<<<N_ATOMS / 16, 256, 0, stream>>>(
        t0, t1, t2, slotOf, agg, wfpre, b0, actw, o0, o1, o2);
}

// Round 10
// 248.843 us; speedup vs baseline: 1.1832x; 1.1832x over previous
//
#include <hip/hip_runtime.h>
#include <hip/hip_bf16.h>

// Problem constants (SOnEquivalentLayer)
#define N_ATOMS 20000
#define N_EDGES 200000
#define CCH     64      // channels
#define KRBF    20      // radial features
#define RCUT    5.0f
#define INV_NORM 0.1f   // 1/norm_factor
#define PI_F    3.14159265358979323846f
#define MCAP    20000   // message pool capacity (~6x expected ~3.3k active edges)
#define ACAP    6000    // active-atom capacity (~2x expected ~3.0k)
#define XSTRIDE 856     // bf16 elems per atom row in LDS (832 + 24 pad)
#define FLAT    832     // 13*64 values per atom

typedef short v8s __attribute__((ext_vector_type(8)));   // 8 bf16 MFMA A/B frag
typedef short v4s __attribute__((ext_vector_type(4)));   // 4 bf16
typedef float v4f __attribute__((ext_vector_type(4)));   // 4 fp32 MFMA C/D frag

__device__ __forceinline__ float sigm(float x) { return 1.0f / (1.0f + __expf(-x)); }

__device__ __forceinline__ short f2bf(float x) {
    union { float f; unsigned u; } v; v.f = x;
    unsigned r = v.u + 0x7FFFu + ((v.u >> 16) & 1u);
    return (short)(r >> 16);
}
__device__ __forceinline__ float bf2f(short b) {
    union { unsigned u; float f; } v; v.u = ((unsigned)(unsigned short)b) << 16;
    return v.f;
}

// ---------------------------------------------------------------------------
// Phase A: thread-per-edge cutoff filter -> flat compacted message pool
// + CAS first-touch compact-slot allocation. ~1.65% edges survive
// (fc == 0 exactly for d >= RCUT in fp32).
// ---------------------------------------------------------------------------
__global__ __launch_bounds__(256) void edge_filter_kernel(
    const float* __restrict__ coords,
    const int*   __restrict__ edge_index,
    float4*      __restrict__ mu,
    float*       __restrict__ mb,
    int*         __restrict__ maj,
    int*         __restrict__ mai,
    int*         __restrict__ slotOf,
    int*         __restrict__ counters)
{
    const int e = blockIdx.x * 256 + threadIdx.x;
    if (e >= N_EDGES) return;
    const int ai = edge_index[e];
    const int aj = edge_index[N_EDGES + e];

    const float rx = coords[aj * 3 + 0] - coords[ai * 3 + 0];
    const float ry = coords[aj * 3 + 1] - coords[ai * 3 + 1];
    const float rz = coords[aj * 3 + 2] - coords[ai * 3 + 2];
    const float d  = sqrtf(rx * rx + ry * ry + rz * rz + 1e-12f);
    if (d >= RCUT) return;   // fc == 0 exactly -> zero contribution

    const float inv_d = 1.0f / d;
    const float base  = PI_F * (d * (1.0f / RCUT));
    const float fc    = 0.5f * (cosf(base) + 1.0f);
    const float coef  = 0.632455532033676f * fc * inv_d * INV_NORM;

    const int slot = atomicAdd(&counters[0], 1);
    if (slot >= MCAP) return;
    mu[slot]  = make_float4(rx * inv_d, ry * inv_d, rz * inv_d, coef);
    mb[slot]  = base;
    maj[slot] = aj;
    mai[slot] = ai;
    if (atomicCAS(&slotOf[ai], -1, -2) == -1)
        slotOf[ai] = atomicAdd(&counters[1], 1);
}

// ---------------------------------------------------------------------------
// W-fragment precompute: one-time gather into bf16 MFMA B-frags,
// layout [wid][way][half][lane][8] -> si_mfma reads 6 coalesced b128 loads.
// ---------------------------------------------------------------------------
__global__ __launch_bounds__(256) void wfrag_kernel(
    const float* __restrict__ w0,
    const float* __restrict__ w1,
    const float* __restrict__ w2,
    short*       __restrict__ wfpre)        // [4*3*2*64*8]
{
    const int id = blockIdx.x * 256 + threadIdx.x;   // 48*256 = 12288
    const int j    = id & 7;
    const int lane = (id >> 3) & 63;
    const int h    = (id >> 9) & 1;
    const int rest = id >> 10;               // wid*3 + w, in [0,12)
    const int w    = rest % 3;
    const int wid  = rest / 3;
    const float* Ws = (w == 0) ? w0 : (w == 1) ? w1 : w2;
    const int k = h * 32 + (lane >> 4) * 8 + j;      // input channel
    const int o = wid * 16 + (lane & 15);            // output channel
    wfpre[id] = f2bf(Ws[k * CCH + o]);
}

// ---------------------------------------------------------------------------
// Phase B: wave-per-message scan. PLANE-MAJOR agg (agg[(slot*13+p)*64+c]):
// every wave-atomic hits 64 contiguous floats (r9's t-flat strided atomics
// caused a ~10x L2 atomic-transaction storm -> 76us; this was 19us in r7).
// ---------------------------------------------------------------------------
__global__ __launch_bounds__(256, 4) void msg_scan_kernel(
    const float* __restrict__ t0,
    const float* __restrict__ t1,
    const float* __restrict__ t2,
    const float* __restrict__ rbf_w,
    const float4* __restrict__ mu,
    const float* __restrict__ mb,
    const int*   __restrict__ maj,
    const int*   __restrict__ mai,
    const int*   __restrict__ slotOf,
    const int*   __restrict__ counters,
    float*       __restrict__ agg)          // [ACAP * 13 * 64], zero-init
{
    const int w    = (int)((blockIdx.x * 256 + threadIdx.x) >> 6);
    const int c    = threadIdx.x & 63;
    const int nw   = gridDim.x * 4;
    const int nMsg = min(counters[0], MCAP);

    for (int s = w; s < nMsg; s += nw) {
        const float4 U   = mu[s];           // wave-uniform broadcast loads
        const float base = mb[s];
        const int   aj   = maj[s];
        const int   ai   = mai[s];
        const int   sIdx = slotOf[ai];
        if ((unsigned)sIdx >= ACAP) continue;

        float rbf[KRBF];
#pragma unroll
        for (int kk = 0; kk < KRBF; kk++)
            rbf[kk] = U.w * __sinf((float)(kk + 1) * base);

        float fn[11];
#pragma unroll 1
        for (int k = 0; k < 11; k++) {      // unroll 1: cap VGPR pressure
            float acc = 0.0f;
#pragma unroll
            for (int kk = 0; kk < KRBF; kk++)
                acc += rbf[kk] * rbf_w[k * (KRBF * CCH) + kk * CCH + c];
            fn[k] = acc;
        }

        const int cj = aj * CCH + c;
        const float s0 = t0[cj];
        float v[3];
#pragma unroll
        for (int a = 0; a < 3; a++) v[a] = t1[cj * 3 + a];
        float M[9];
#pragma unroll
        for (int e = 0; e < 9; e++) M[e] = t2[cj * 9 + e];

        const float u[3] = { U.x, U.y, U.z };
        const float dvu = v[0] * u[0] + v[1] * u[1] + v[2] * u[2];
        float Mu[3];
#pragma unroll
        for (int a = 0; a < 3; a++)
            Mu[a] = M[a * 3] * u[0] + M[a * 3 + 1] * u[1] + M[a * 3 + 2] * u[2];
        const float uMu = u[0] * Mu[0] + u[1] * Mu[1] + u[2] * Mu[2];

        float* dst = agg + ((size_t)sIdx * 13) * CCH + c;
        atomicAdd(&dst[0], fn[0] * s0 + fn[4] * dvu + fn[9] * uMu);
#pragma unroll
        for (int a = 0; a < 3; a++)
            atomicAdd(&dst[(1 + a) * CCH],
                      fn[1] * s0 * u[a] + fn[3] * v[a] + fn[6] * dvu * u[a] + fn[8] * Mu[a]);
#pragma unroll
        for (int a = 0; a < 3; a++) {
            const float ta = fn[2] * s0 * u[a] + fn[5] * v[a] + fn[10] * Mu[a];
#pragma unroll
            for (int b = 0; b < 3; b++)
                atomicAdd(&dst[(4 + a * 3 + b) * CCH], ta * u[b] + fn[7] * M[a * 3 + b]);
        }
    }
}

// ---------------------------------------------------------------------------
// Phase C: MFMA self-interaction, fully-coalesced VMEM on both layouts:
//   staging:  13x dwordx4 t-flat loads -> bf16 LDS transpose (no slot logic)
//   agg add:  plane-major coalesced reads, wave-per-plane LDS RMW,
//             block-uniform skip for inactive atoms (~85%)
//   MFMA:     26x mfma_f32_16x16x32_bf16; W-frags: 6 coalesced b128 loads
//   epilogue: gates+residual RMW in-place (lane-owned), 13x dwordx4 stores
// ---------------------------------------------------------------------------
__global__ __launch_bounds__(256, 4) void si_mfma_kernel(
    const float* __restrict__ t0,
    const float* __restrict__ t1,
    const float* __restrict__ t2,
    const int*   __restrict__ slotOf,
    const float* __restrict__ agg,          // [ACAP * 13 * 64], plane-major
    const short* __restrict__ wfpre,        // [4][3][2][64][8] bf16
    const float* __restrict__ b0,
    const float* __restrict__ actw,
    float* __restrict__ out0,
    float* __restrict__ out1,
    float* __restrict__ out2)
{
    __shared__ __align__(16) short Xl[16 * XSTRIDE];   // 27.4 KB
    const int tid  = threadIdx.x;
    const int lane = tid & 63;
    const int wid  = tid >> 6;
    const int n0   = blockIdx.x * 16;

    const int ocol = wid * 16 + (lane & 15);
    // --- W fragments: 6 coalesced b128 loads ---
    v8s wf[3][2];
#pragma unroll
    for (int w = 0; w < 3; w++)
#pragma unroll
        for (int h = 0; h < 2; h++)
            wf[w][h] = *(const v8s*)&wfpre[(((wid * 3 + w) * 2 + h) * 64 + lane) * 8];

    // --- staging: 13 coalesced dwordx4 loads -> bf16 LDS transpose ---
#pragma unroll 1
    for (int i = 0; i < 13; i++) {
        const int f4   = tid + i * 256;          // [0, 3328)
        const int atom = f4 / 208;               // 208 float4 per atom
        const int f    = (f4 - atom * 208) * 4;  // element offset in [0,832)
        const int n    = n0 + atom;
        const float* src;
        if (f < 64)       src = t0 + (size_t)n * 64 + f;
        else if (f < 256) src = t1 + (size_t)n * 192 + (f - 64);
        else              src = t2 + (size_t)n * 576 + (f - 256);
        const float4 v = *(const float4*)src;
        short* xr = &Xl[atom * XSTRIDE];
        if (f < 64) {
            v4s p; p[0] = f2bf(v.x); p[1] = f2bf(v.y); p[2] = f2bf(v.z); p[3] = f2bf(v.w);
            *(v4s*)&xr[f] = p;                   // plane 0 contiguous
        } else if (f < 256) {
            const int r0 = f - 64;
            const float vv[4] = { v.x, v.y, v.z, v.w };
#pragma unroll
            for (int j = 0; j < 4; j++) {
                const int rem = r0 + j;
                xr[(1 + rem % 3) * 64 + rem / 3] = f2bf(vv[j]);
            }
        } else {
            const int r0 = f - 256;
            const float vv[4] = { v.x, v.y, v.z, v.w };
#pragma unroll
            for (int j = 0; j < 4; j++) {
                const int rem = r0 + j;
                xr[(4 + rem % 9) * 64 + rem / 9] = f2bf(vv[j]);
            }
        }
    }
    __syncthreads();

    // --- agg add: plane-major coalesced reads, block-uniform active test ---
    {
        const int c = lane;
#pragma unroll 1
        for (int atom = 0; atom < 16; atom++) {
            const int slot = slotOf[n0 + atom];      // broadcast load, L2-hot
            if ((unsigned)slot >= ACAP) continue;    // block-uniform skip
            short* xr = &Xl[atom * XSTRIDE];
            const float* ap = agg + ((size_t)slot * 13) * CCH + c;
#pragma unroll 1
            for (int pp = wid; pp < 13; pp += 4) {   // wave p owns planes p,p+4,..
                const int off = pp * CCH + c;
                xr[off] = f2bf(bf2f(xr[off]) + ap[pp * CCH]);
            }
        }
    }
    __syncthreads();

    // --- 26 MFMAs: 13 planes x 2 k-halves ---
    v4f acc[13] = {};
    const int abase = (lane & 15) * XSTRIDE + (lane >> 4) * 8;
#pragma unroll
    for (int p = 0; p < 13; p++) {
        const int w = (p == 0) ? 0 : (p < 4 ? 1 : 2);
#pragma unroll
        for (int h = 0; h < 2; h++) {
            const v8s a = *(const v8s*)&Xl[abase + p * CCH + h * 32];
            acc[p] = __builtin_amdgcn_mfma_f32_16x16x32_bf16(a, wf[w][h], acc[p], 0, 0, 0);
        }
    }
    __syncthreads();   // all MFMA A-reads done before in-place overwrite

    // --- epilogue: gates + residual, RMW in-place (lane-owned positions) ---
    const float aw0  = actw[ocol];
    const float aw1  = actw[CCH + ocol];
    const float aw2  = actw[2 * CCH + ocol];
    const float bias = b0[ocol];
#pragma unroll
    for (int r = 0; r < 4; r++) {
        const int al = (lane >> 4) * 4 + r;      // atom-in-block (C/D row)
        short* xr = &Xl[al * XSTRIDE];

        const float y0 = acc[0][r] + bias;
        const float z0 = y0 * sigm(aw0 * y0);
        xr[ocol] = f2bf(z0 + bf2f(xr[ocol]));

        float nn = 1e-12f;
#pragma unroll
        for (int a = 0; a < 3; a++) nn += acc[1 + a][r] * acc[1 + a][r];
        const float g1 = sigm(aw1 * sqrtf(nn));
#pragma unroll
        for (int a = 0; a < 3; a++) {
            const int off = (1 + a) * CCH + ocol;
            xr[off] = f2bf(acc[1 + a][r] * g1 + bf2f(xr[off]));
        }

        float s2 = 1e-12f;
#pragma unroll
        for (int e = 0; e < 9; e++) s2 += acc[4 + e][r] * acc[4 + e][r];
        const float g2 = sigm(aw2 * sqrtf(s2));
#pragma unroll
        for (int e = 0; e < 9; e++) {
            const int off = (4 + e) * CCH + ocol;
            xr[off] = f2bf(acc[4 + e][r] * g2 + bf2f(xr[off]));
        }
    }
    __syncthreads();

    // --- store: 13 coalesced dwordx4 stores mirroring staging mapping ---
#pragma unroll 1
    for (int i = 0; i < 13; i++) {
        const int f4   = tid + i * 256;
        const int atom = f4 / 208;
        const int f    = (f4 - atom * 208) * 4;
        const int n    = n0 + atom;
        const short* xr = &Xl[atom * XSTRIDE];
        float4 v;
        float* dst;
        if (f < 64) {
            const v4s p = *(const v4s*)&xr[f];
            v.x = bf2f(p[0]); v.y = bf2f(p[1]); v.z = bf2f(p[2]); v.w = bf2f(p[3]);
            dst = out0 + (size_t)n * 64 + f;
        } else if (f < 256) {
            const int r0 = f - 64;
            float vv[4];
#pragma unroll
            for (int j = 0; j < 4; j++) {
                const int rem = r0 + j;
                vv[j] = bf2f(xr[(1 + rem % 3) * 64 + rem / 3]);
            }
            v.x = vv[0]; v.y = vv[1]; v.z = vv[2]; v.w = vv[3];
            dst = out1 + (size_t)n * 192 + r0;
        } else {
            const int r0 = f - 256;
            float vv[4];
#pragma unroll
            for (int j = 0; j < 4; j++) {
                const int rem = r0 + j;
                vv[j] = bf2f(xr[(4 + rem % 9) * 64 + rem / 9]);
            }
            v.x = vv[0]; v.y = vv[1]; v.z = vv[2]; v.w = vv[3];
            dst = out2 + (size_t)n * 576 + r0;
        }
        *(float4*)dst = v;
    }
}

extern "C" void kernel_launch(void* const* d_in, const int* in_sizes, int n_in,
                              void* d_out, int out_size, void* d_ws, size_t ws_size,
                              hipStream_t stream) {
    const float* t0     = (const float*)d_in[0];
    const float* t1     = (const float*)d_in[1];
    const float* t2     = (const float*)d_in[2];
    const float* coords = (const float*)d_in[3];
    const int*   eidx   = (const int*)d_in[4];
    const float* rbfw   = (const float*)d_in[5];
    const float* w0     = (const float*)d_in[6];
    const float* b0     = (const float*)d_in[7];
    const float* w1     = (const float*)d_in[8];
    const float* w2     = (const float*)d_in[9];
    const float* actw   = (const float*)d_in[10];

    // Workspace: agg | mu | mb | maj | mai | wfpre | slotOf | counters
    float*  agg    = (float*)d_ws;                       // ACAP*832 floats (20 MB)
    float4* mu     = (float4*)(agg + (size_t)ACAP * FLAT);
    float*  mb     = (float*)(mu + MCAP);
    int*    maj    = (int*)(mb + MCAP);
    int*    mai    = maj + MCAP;
    short*  wfpre  = (short*)(mai + MCAP);               // 12288 bf16 (24.6 KB)
    int*    slotOf = (int*)(wfpre + 12288);
    int*    counters = slotOf + N_ATOMS;
    const size_t wsNeed = (size_t)ACAP * FLAT * 4 + (size_t)MCAP * 28
                        + 12288 * 2 + (size_t)N_ATOMS * 4 + 64;
    if (ws_size < wsNeed) return;

    hipMemsetAsync(agg, 0, (size_t)ACAP * FLAT * sizeof(float), stream);  // 20 MB
    hipMemsetAsync(slotOf, 0xFF, (size_t)N_ATOMS * sizeof(int), stream);
    hipMemsetAsync(counters, 0, 2 * sizeof(int), stream);

    float* o0 = (float*)d_out;
    float* o1 = o0 + (size_t)N_ATOMS * CCH;
    float* o2 = o1 + (size_t)N_ATOMS * CCH * 3;

    edge_filter_kernel<<<(N_EDGES + 255) / 256, 256, 0, stream>>>(
        coords, eidx, mu, mb, maj, mai, slotOf, counters);

    wfrag_kernel<<<48, 256, 0, stream>>>(w0, w1, w2, wfpre);

    msg_scan_kernel<<<224, 256, 0, stream>>>(
        t0, t1, t2, rbfw, mu, mb, maj, mai, slotOf, counters, agg);

    si_mfma_kernel<<<N_ATOMS / 16, 256, 0, stream>>>(
        t0, t1, t2, slotOf, agg, wfpre, b0, actw, o0, o1, o2);
}